// Round 2
// baseline (10816.848 us; speedup 1.0000x reference)
//
#include <hip/hip_runtime.h>
#include <hip/hip_bf16.h>

#define Bsz 256
#define Tlen 512
#define Dd 512
#define Hh 1024
#define G4 4096
#define NOUT 8
#define BT (Bsz * Tlen)

typedef short s16x8 __attribute__((ext_vector_type(8)));
typedef float f32x4 __attribute__((ext_vector_type(4)));

__device__ __forceinline__ ushort f2bf(float f) {
    union { float f; uint u; } v; v.f = f;
    uint u = v.u;
    uint r = u + 0x7FFFu + ((u >> 16) & 1u);   // round-to-nearest-even
    return (ushort)(r >> 16);
}
__device__ __forceinline__ float bf2f(ushort u) {
    union { uint u; float f; } v; v.u = ((uint)u) << 16; return v.f;
}
__device__ __forceinline__ float sigf(float x) { return 1.f / (1.f + __expf(-x)); }
__device__ __forceinline__ float tanhfast(float x) {
    float ax = fabsf(x);
    float e = __expf(-2.f * ax);
    float t = (1.f - e) / (1.f + e);
    return copysignf(t, x);
}

// async global->LDS, 16B per lane; LDS base must be wave-uniform (HW adds lane*16)
__device__ __forceinline__ void gload16(const void* g, void* l) {
    __builtin_amdgcn_global_load_lds(
        (const __attribute__((address_space(1))) uint*)g,
        (__attribute__((address_space(3))) uint*)l, 16, 0, 0);
}

// xproj element store/load (bf16 or fp32 tier)
__device__ __forceinline__ void xp_store(ushort* p, float v) { *p = f2bf(v); }
__device__ __forceinline__ void xp_store(float* p, float v) { *p = v; }
__device__ __forceinline__ float xp_load(const ushort* p) { return bf2f(*p); }
__device__ __forceinline__ float xp_load(const float* p) { return *p; }

// ---------------- init: zero h0 (bf16) and c (fp32) ----------------
__global__ void init_kernel(uint4* __restrict__ h0, uint4* __restrict__ c) {
    int i = blockIdx.x * 256 + threadIdx.x;       // 65536 threads
    uint4 z = make_uint4(0u, 0u, 0u, 0u);
    c[i] = z;                                     // 65536 uint4 = 1 MB
    if (i < 32768) h0[i] = z;                     // 32768 uint4 = 512 KB
}

// ---------------- fp32 -> bf16 convert ----------------
__global__ void cvt_kernel(const float4* __restrict__ src, ushort4* __restrict__ dst, int n4) {
    int i = blockIdx.x * 256 + threadIdx.x;
    if (i >= n4) return;
    float4 v = src[i];
    ushort4 w;
    w.x = f2bf(v.x); w.y = f2bf(v.y); w.z = f2bf(v.z); w.w = f2bf(v.w);
    dst[i] = w;
}

// ---------------- x_proj GEMM: xproj[t][b][g] = x[b,t,:]*W_ih[g,:] + b_ih[g]+b_hh[g] ----
// A = xb bf16 [BT][512] (row = b*512+t), B = Wih bf16 [4096][512]
// tile 128x128, BK=64, 256 threads / 4 waves (each wave 64x64), 2-phase gload_lds.
template <typename XT>
__launch_bounds__(256)
__global__ void xproj_gemm(const ushort* __restrict__ xb,
                           const ushort* __restrict__ Wih,
                           const float* __restrict__ b_ih,
                           const float* __restrict__ b_hh,
                           XT* __restrict__ xproj) {
    __shared__ ushort As[2][128 * 64];
    __shared__ ushort Bs[2][128 * 64];
    const int tid  = threadIdx.x;
    const int lane = tid & 63;
    const int wid  = tid >> 6;      // 0..3
    const int wr   = wid >> 1;
    const int wc   = wid & 1;
    const int mt   = blockIdx.x >> 5;   // 0..1023
    const int nt   = blockIdx.x & 31;   // 0..31
    const int m0   = mt * 128;
    const int n0   = nt * 128;

    f32x4 acc[4][4] = {};

    auto stage = [&](int buf, int kb) {
        const int k0 = kb << 6;
        #pragma unroll
        for (int ii = 0; ii < 4; ++ii) {
            const int inst = (wid << 2) + ii;   // 0..15
            const int r0 = inst << 3;
            const int r  = r0 + (lane >> 3);
            const int ch = lane & 7;
            const int sw = (ch ^ (r & 7)) << 3;
            gload16(&xb[(size_t)(m0 + r) * Dd + k0 + sw], &As[buf][r0 * 64]);
            gload16(&Wih[(size_t)(n0 + r) * Dd + k0 + sw], &Bs[buf][r0 * 64]);
        }
    };
    auto compute = [&](int buf) {
        #pragma unroll
        for (int ks = 0; ks < 2; ++ks) {
            const int kc = (ks << 2) + (lane >> 4);
            s16x8 a[4], b[4];
            #pragma unroll
            for (int m = 0; m < 4; ++m) {
                int row = (wr << 6) + (m << 4) + (lane & 15);
                a[m] = *(const s16x8*)&As[buf][row * 64 + ((kc ^ (row & 7)) << 3)];
            }
            #pragma unroll
            for (int n = 0; n < 4; ++n) {
                int col = (wc << 6) + (n << 4) + (lane & 15);
                b[n] = *(const s16x8*)&Bs[buf][col * 64 + ((kc ^ (col & 7)) << 3)];
            }
            #pragma unroll
            for (int m = 0; m < 4; ++m)
                #pragma unroll
                for (int n = 0; n < 4; ++n)
                    acc[m][n] = __builtin_amdgcn_mfma_f32_16x16x32_bf16(a[m], b[n], acc[m][n], 0, 0, 0);
        }
    };

    stage(0, 0);
    __syncthreads();
    for (int kb = 0; kb < 8; ++kb) {
        if (kb < 7) stage((kb + 1) & 1, kb + 1);
        compute(kb & 1);
        __syncthreads();
    }

    // epilogue: bias + store to xproj[t][b][gcol]
    float bias[4];
    #pragma unroll
    for (int n = 0; n < 4; ++n) {
        int gcol = n0 + (wc << 6) + (n << 4) + (lane & 15);
        bias[n] = b_ih[gcol] + b_hh[gcol];
    }
    #pragma unroll
    for (int m = 0; m < 4; ++m)
        #pragma unroll
        for (int n = 0; n < 4; ++n)
            #pragma unroll
            for (int j = 0; j < 4; ++j) {
                int grow = m0 + (wr << 6) + (m << 4) + ((lane >> 4) << 2) + j; // = b*512+t
                int gcol = n0 + (wc << 6) + (n << 4) + (lane & 15);
                int b_ = grow >> 9, t_ = grow & 511;
                xp_store(&xproj[((size_t)t_ * Bsz + b_) * G4 + gcol], acc[m][n][j] + bias[n]);
            }
}

// ---------------- one LSTM time step (K=1024 recurrent only) ----------------
// grid 256 (4 batch-tiles x 64 col-tiles), 512 threads = 8 waves.
// K split across 2 wave-groups (waves 0-3: k<512, waves 4-7: k>=512), each group
// 2-phase pipelined over 8 K-iters of 64; LDS reduce; fused activations.
template <typename XT>
__launch_bounds__(512)
__global__ void lstm_step2(const XT* __restrict__ xproj,     // [T][B][4096] incl. biases
                           const ushort* __restrict__ Whh,   // bf16 [4096][1024]
                           const ushort* __restrict__ h_prev,// bf16 [256][1024]
                           ushort* __restrict__ h_next,
                           float* __restrict__ c,
                           int t) {
    __shared__ ushort At[2][2][64 * 64];   // [group][buf]
    __shared__ ushort Bt[2][2][64 * 64];
    __shared__ float gates[64 * 66];

    const int tid  = threadIdx.x;
    const int lane = tid & 63;
    const int wid  = tid >> 6;      // 0..7
    const int grp  = wid >> 2;      // K-half
    const int w4   = wid & 3;
    const int wr   = w4 >> 1;
    const int wc   = w4 & 1;
    const int bt   = blockIdx.x >> 6;
    const int jt   = blockIdx.x & 63;
    const int b0   = bt * 64;
    const int j0   = jt * 16;

    f32x4 acc[2][2] = {};

    auto stage = [&](int buf, int kb) {
        const int k0 = (grp << 9) + (kb << 6);
        #pragma unroll
        for (int ii = 0; ii < 2; ++ii) {
            const int inst = (w4 << 1) + ii;    // 0..7
            const int r0 = inst << 3;
            const int r  = r0 + (lane >> 3);
            const int ch = lane & 7;
            const int sw = (ch ^ (r & 7)) << 3;
            gload16(&h_prev[(size_t)(b0 + r) * Hh + k0 + sw], &At[grp][buf][r0 * 64]);
            const int grow = ((r >> 4) << 10) + j0 + (r & 15);
            gload16(&Whh[(size_t)grow * Hh + k0 + sw], &Bt[grp][buf][r0 * 64]);
        }
    };
    auto compute = [&](int buf) {
        #pragma unroll
        for (int ks = 0; ks < 2; ++ks) {
            const int kc = (ks << 2) + (lane >> 4);
            s16x8 a[2], b[2];
            #pragma unroll
            for (int m = 0; m < 2; ++m) {
                int row = (wr << 5) + (m << 4) + (lane & 15);
                a[m] = *(const s16x8*)&At[grp][buf][row * 64 + ((kc ^ (row & 7)) << 3)];
            }
            #pragma unroll
            for (int n = 0; n < 2; ++n) {
                int col = (wc << 5) + (n << 4) + (lane & 15);
                b[n] = *(const s16x8*)&Bt[grp][buf][col * 64 + ((kc ^ (col & 7)) << 3)];
            }
            #pragma unroll
            for (int m = 0; m < 2; ++m)
                #pragma unroll
                for (int n = 0; n < 2; ++n)
                    acc[m][n] = __builtin_amdgcn_mfma_f32_16x16x32_bf16(a[m], b[n], acc[m][n], 0, 0, 0);
        }
    };

    stage(0, 0);
    __syncthreads();
    for (int kb = 0; kb < 8; ++kb) {
        if (kb < 7) stage((kb + 1) & 1, kb + 1);
        compute(kb & 1);
        __syncthreads();
    }

    // reduce the two K-halves through LDS
    if (grp == 0) {
        #pragma unroll
        for (int m = 0; m < 2; ++m)
            #pragma unroll
            for (int n = 0; n < 2; ++n)
                #pragma unroll
                for (int j = 0; j < 4; ++j) {
                    int row = (wr << 5) + (m << 4) + ((lane >> 4) << 2) + j;
                    int col = (wc << 5) + (n << 4) + (lane & 15);
                    gates[row * 66 + col] = acc[m][n][j];
                }
    }
    __syncthreads();
    if (grp == 1) {
        #pragma unroll
        for (int m = 0; m < 2; ++m)
            #pragma unroll
            for (int n = 0; n < 2; ++n)
                #pragma unroll
                for (int j = 0; j < 4; ++j) {
                    int row = (wr << 5) + (m << 4) + ((lane >> 4) << 2) + j;
                    int col = (wc << 5) + (n << 4) + (lane & 15);
                    gates[row * 66 + col] += acc[m][n][j];
                }
    }
    __syncthreads();

    // activations + cell update: 64 rows x 16 h-cols, 2 elems/thread
    const XT* xp_t = xproj + (size_t)t * Bsz * G4;
    #pragma unroll
    for (int it = 0; it < 2; ++it) {
        int idx = tid + it * 512;               // 0..1023
        int row = idx >> 4;
        int cc  = idx & 15;
        int gcol = j0 + cc;
        const XT* xp = xp_t + (size_t)(b0 + row) * G4 + gcol;
        float gi = gates[row * 66 + cc]      + xp_load(xp);
        float gf = gates[row * 66 + 16 + cc] + xp_load(xp + Hh);
        float gg = gates[row * 66 + 32 + cc] + xp_load(xp + 2 * Hh);
        float go = gates[row * 66 + 48 + cc] + xp_load(xp + 3 * Hh);
        float i_ = sigf(gi);
        float f_ = sigf(gf);
        float g_ = tanhfast(gg);
        float o_ = sigf(go);
        size_t cidx = (size_t)(b0 + row) * Hh + gcol;
        float cn = f_ * c[cidx] + i_ * g_;
        c[cidx] = cn;
        float hn = o_ * tanhfast(cn);
        h_next[cidx] = f2bf(hn);
    }
}

// ---------------- FALLBACK: round-0 fused step (used when ws too small) ----------------
__launch_bounds__(256)
__global__ void lstm_step_fused(const float* __restrict__ x,
                          const ushort* __restrict__ Wih,
                          const ushort* __restrict__ Whh,
                          const float* __restrict__ b_ih,
                          const float* __restrict__ b_hh,
                          const ushort* __restrict__ h_prev,
                          ushort* __restrict__ h_next,
                          float* __restrict__ c,
                          int t) {
    __shared__ ushort At[64 * 64];
    __shared__ ushort Bt[64 * 64];
    __shared__ float gates[64 * 72];

    const int tid  = threadIdx.x;
    const int lane = tid & 63;
    const int wid  = tid >> 6;
    const int wr   = wid >> 1;
    const int wc   = wid & 1;
    const int bt   = blockIdx.x >> 6;
    const int jt   = blockIdx.x & 63;
    const int b0   = bt * 64;
    const int j0   = jt * 16;

    f32x4 acc[2][2] = {};

    auto mfma_tile = [&]() {
        #pragma unroll
        for (int ks = 0; ks < 2; ++ks) {
            const int kc = (ks << 2) + (lane >> 4);
            s16x8 a[2], bfr[2];
            #pragma unroll
            for (int m = 0; m < 2; ++m) {
                int row = wr * 32 + m * 16 + (lane & 15);
                a[m] = *(const s16x8*)&At[row * 64 + ((kc ^ (row & 7)) << 3)];
            }
            #pragma unroll
            for (int n = 0; n < 2; ++n) {
                int col = wc * 32 + n * 16 + (lane & 15);
                bfr[n] = *(const s16x8*)&Bt[col * 64 + ((kc ^ (col & 7)) << 3)];
            }
            #pragma unroll
            for (int m = 0; m < 2; ++m)
                #pragma unroll
                for (int n = 0; n < 2; ++n)
                    acc[m][n] = __builtin_amdgcn_mfma_f32_16x16x32_bf16(a[m], bfr[n], acc[m][n], 0, 0, 0);
        }
    };

    for (int kb = 0; kb < Dd; kb += 64) {
        __syncthreads();
        #pragma unroll
        for (int it = 0; it < 4; ++it) {
            int idx = tid + it * 256;
            int row = idx >> 4;
            int k   = (idx & 15) * 4;
            const float4 v = *(const float4*)&x[(size_t)(b0 + row) * (Tlen * Dd) + (size_t)t * Dd + kb + k];
            ushort4 w;
            w.x = f2bf(v.x); w.y = f2bf(v.y); w.z = f2bf(v.z); w.w = f2bf(v.w);
            int dst = row * 64 + (((k >> 3) ^ (row & 7)) << 3) + (k & 7);
            *(ushort4*)&At[dst] = w;
        }
        #pragma unroll
        for (int it = 0; it < 2; ++it) {
            int idx = tid + it * 256;
            int col = idx >> 3;
            int kc  = idx & 7;
            int grow = ((col >> 4) << 10) + j0 + (col & 15);
            uint4 v = *(const uint4*)&Wih[(size_t)grow * Dd + kb + kc * 8];
            *(uint4*)&Bt[col * 64 + ((kc ^ (col & 7)) << 3)] = v;
        }
        __syncthreads();
        mfma_tile();
    }
    for (int kb = 0; kb < Hh; kb += 64) {
        __syncthreads();
        #pragma unroll
        for (int it = 0; it < 2; ++it) {
            int idx = tid + it * 256;
            int row = idx >> 3;
            int kc  = idx & 7;
            uint4 v = *(const uint4*)&h_prev[(size_t)(b0 + row) * Hh + kb + kc * 8];
            *(uint4*)&At[row * 64 + ((kc ^ (row & 7)) << 3)] = v;
        }
        #pragma unroll
        for (int it = 0; it < 2; ++it) {
            int idx = tid + it * 256;
            int col = idx >> 3;
            int kc  = idx & 7;
            int grow = ((col >> 4) << 10) + j0 + (col & 15);
            uint4 v = *(const uint4*)&Whh[(size_t)grow * Hh + kb + kc * 8];
            *(uint4*)&Bt[col * 64 + ((kc ^ (col & 7)) << 3)] = v;
        }
        __syncthreads();
        mfma_tile();
    }

    #pragma unroll
    for (int m = 0; m < 2; ++m)
        #pragma unroll
        for (int n = 0; n < 2; ++n)
            #pragma unroll
            for (int j = 0; j < 4; ++j) {
                int row = wr * 32 + m * 16 + ((lane >> 4) << 2) + j;
                int col = wc * 32 + n * 16 + (lane & 15);
                gates[row * 72 + col] = acc[m][n][j];
            }
    __syncthreads();

    #pragma unroll
    for (int it = 0; it < 4; ++it) {
        int idx = tid + it * 256;
        int row = idx >> 4;
        int cc  = idx & 15;
        int gcol = j0 + cc;
        float gi = gates[row * 72 + cc]      + b_ih[gcol]          + b_hh[gcol];
        float gf = gates[row * 72 + 16 + cc] + b_ih[Hh + gcol]     + b_hh[Hh + gcol];
        float gg = gates[row * 72 + 32 + cc] + b_ih[2 * Hh + gcol] + b_hh[2 * Hh + gcol];
        float go = gates[row * 72 + 48 + cc] + b_ih[3 * Hh + gcol] + b_hh[3 * Hh + gcol];
        float i_ = sigf(gi);
        float f_ = sigf(gf);
        float g_ = tanhfast(gg);
        float o_ = sigf(go);
        size_t cidx = (size_t)(b0 + row) * Hh + gcol;
        float cn = f_ * c[cidx] + i_ * g_;
        c[cidx] = cn;
        float hn = o_ * tanhfast(cn);
        h_next[cidx] = f2bf(hn);
    }
}

// ---------------- FC head ----------------
__global__ void fc_kernel(const ushort* __restrict__ h,
                          const float* __restrict__ Wfc,
                          const float* __restrict__ bfc,
                          float* __restrict__ out) {
    int b = blockIdx.x;
    int w = threadIdx.x >> 6;
    int lane = threadIdx.x & 63;
    float s = 0.f;
    for (int k = lane; k < Hh; k += 64)
        s += bf2f(h[(size_t)b * Hh + k]) * Wfc[w * Hh + k];
    #pragma unroll
    for (int off = 32; off; off >>= 1) s += __shfl_down(s, off);
    if (lane == 0) out[b * NOUT + w] = sigf(s + bfc[w]);
}

extern "C" void kernel_launch(void* const* d_in, const int* in_sizes, int n_in,
                              void* d_out, int out_size, void* d_ws, size_t ws_size,
                              hipStream_t stream) {
    const float* x    = (const float*)d_in[0];
    const float* W_ih = (const float*)d_in[1];
    const float* W_hh = (const float*)d_in[2];
    const float* b_ih = (const float*)d_in[3];
    const float* b_hh = (const float*)d_in[4];
    const float* W_fc = (const float*)d_in[5];
    const float* b_fc = (const float*)d_in[6];
    float* out = (float*)d_out;

    char* ws = (char*)d_ws;
    // ws layout:
    //   [0, 1 MB)       h ping-pong bf16 [2][256][1024]
    //   [1, 2 MB)       c fp32
    //   [2, 6 MB)       W_ih bf16
    //   [6, 14 MB)      W_hh bf16
    //   [14, 142 MB)    x bf16 [131072][512]
    //   [142 MB, ...)   x_proj [512][256][4096] (bf16 1 GB or fp32 2 GB)
    ushort* h_buf  = (ushort*)ws;
    float*  c_ws   = (float*)(ws + (1ull << 20));
    ushort* wih_bf = (ushort*)(ws + (2ull << 20));
    ushort* whh_bf = (ushort*)(ws + (6ull << 20));
    ushort* x_bf   = (ushort*)(ws + (14ull << 20));
    char*   xp_p   = ws + (142ull << 20);

    const size_t xp_elems = (size_t)Tlen * Bsz * G4;
    const size_t need_b16 = (142ull << 20) + xp_elems * 2;
    const size_t need_f32 = (142ull << 20) + xp_elems * 4;

    init_kernel<<<256, 256, 0, stream>>>((uint4*)h_buf, (uint4*)c_ws);
    cvt_kernel<<<(G4 * Dd / 4) / 256, 256, 0, stream>>>((const float4*)W_ih, (ushort4*)wih_bf, G4 * Dd / 4);
    cvt_kernel<<<(G4 * Hh / 4) / 256, 256, 0, stream>>>((const float4*)W_hh, (ushort4*)whh_bf, G4 * Hh / 4);

    if (ws_size >= need_b16) {
        // main path: precompute x_proj with one big GEMM, steps do K=1024 only
        cvt_kernel<<<(BT * Dd / 4) / 256, 256, 0, stream>>>((const float4*)x, (ushort4*)x_bf, BT * Dd / 4);
        const int gemm_grid = (BT / 128) * (G4 / 128);     // 32768
        if (ws_size >= need_f32) {
            float* xp = (float*)xp_p;
            xproj_gemm<float><<<gemm_grid, 256, 0, stream>>>(x_bf, wih_bf, b_ih, b_hh, xp);
            for (int t = 0; t < Tlen; ++t) {
                const ushort* hp = h_buf + (size_t)(t & 1) * Bsz * Hh;
                ushort*       hn = h_buf + (size_t)((t + 1) & 1) * Bsz * Hh;
                lstm_step2<float><<<256, 512, 0, stream>>>(xp, whh_bf, hp, hn, c_ws, t);
            }
        } else {
            ushort* xp = (ushort*)xp_p;
            xproj_gemm<ushort><<<gemm_grid, 256, 0, stream>>>(x_bf, wih_bf, b_ih, b_hh, xp);
            for (int t = 0; t < Tlen; ++t) {
                const ushort* hp = h_buf + (size_t)(t & 1) * Bsz * Hh;
                ushort*       hn = h_buf + (size_t)((t + 1) & 1) * Bsz * Hh;
                lstm_step2<ushort><<<256, 512, 0, stream>>>(xp, whh_bf, hp, hn, c_ws, t);
            }
        }
    } else {
        // fallback: fused per-step (round-0 path)
        for (int t = 0; t < Tlen; ++t) {
            const ushort* hp = h_buf + (size_t)(t & 1) * Bsz * Hh;
            ushort*       hn = h_buf + (size_t)((t + 1) & 1) * Bsz * Hh;
            lstm_step_fused<<<256, 256, 0, stream>>>(x, wih_bf, whh_bf, b_ih, b_hh, hp, hn, c_ws, t);
        }
    }
    // after 512 steps (even), final h is in buffer 0
    fc_kernel<<<256, 512, 0, stream>>>(h_buf, W_fc, b_fc, out);
}